// Round 3
// baseline (409.356 us; speedup 1.0000x reference)
//
#include <hip/hip_runtime.h>
#include <hip/hip_bf16.h>

// Detect head: prep (fp32->bf16 convert + x transpose) then fused MFMA GEMM + decode.
// Level 0: x0[8,256,64,64], W0[1548,256]  -> out rows [0, 73728)  per batch
// Level 1: x1[8,512,32,32], W1[1548,512]  -> out rows [73728, 92160) per batch
// out: [8, 92160, 86] fp32
// R3: epilogue coalescing — decode -> LDS tile -> contiguous float2 stores.

typedef __attribute__((ext_vector_type(8))) short short8;
typedef __attribute__((ext_vector_type(4))) short short4v;
typedef __attribute__((ext_vector_type(4))) float f32x4;
typedef unsigned int u32;

__device__ __forceinline__ unsigned short f2bf(float f) {
    union { float f; unsigned u; } c; c.f = f;
    return (unsigned short)((c.u + 0x7fffu + ((c.u >> 16) & 1u)) >> 16);  // RTNE
}
__device__ __forceinline__ float sigm(float v) {
    return 1.0f / (1.0f + __expf(-v));
}
__device__ __forceinline__ void gload16(const void* g, void* l) {
    __builtin_amdgcn_global_load_lds(
        (const __attribute__((address_space(1))) u32*)g,
        (__attribute__((address_space(3))) u32*)l, 16, 0, 0);
}

#define OUT_CH 1548
#define NCHN   86
#define BPB    7925760   // per-batch output elements = 92160*86

// ---------------- prep kernels ----------------

__global__ void conv_w_kernel(const float* __restrict__ W, unsigned short* __restrict__ Wb, int n4) {
    int i = blockIdx.x * blockDim.x + threadIdx.x;
    if (i >= n4) return;
    const float4 f = ((const float4*)W)[i];
    short4v v;
    v[0] = (short)f2bf(f.x); v[1] = (short)f2bf(f.y);
    v[2] = (short)f2bf(f.z); v[3] = (short)f2bf(f.w);
    ((short4v*)Wb)[i] = v;
}

// x [B][C][GG] fp32 -> Xb [B][GG][C] bf16 (64x64 LDS tile transpose)
__global__ void transpose_x_kernel(const float* __restrict__ X, unsigned short* __restrict__ Xb,
                                   int C, int GG) {
    __shared__ float sT[64][65];
    const int p0 = blockIdx.x * 64;
    const int c0 = blockIdx.y * 64;
    const int b  = blockIdx.z;
    const int tid = threadIdx.x;
    const float* src = X + ((size_t)b * C + c0) * GG + p0;
    const int rc = tid >> 4;           // base c row
    const int cp = (tid & 15) * 4;     // pixel within tile (float4)
    #pragma unroll
    for (int rr = 0; rr < 4; ++rr) {
        const int c = rc + rr * 16;
        const float4 f = *(const float4*)&src[(size_t)c * GG + cp];
        sT[c][cp + 0] = f.x; sT[c][cp + 1] = f.y;
        sT[c][cp + 2] = f.z; sT[c][cp + 3] = f.w;
    }
    __syncthreads();
    const int p  = tid >> 2;           // pixel row 0..63
    const int cg = (tid & 3) * 16;     // channel group
    unsigned short u[16];
    #pragma unroll
    for (int k = 0; k < 16; ++k) u[k] = f2bf(sT[cg + k][p]);
    unsigned short* dst = Xb + ((size_t)b * GG + p0 + p) * C + c0 + cg;
    *(short8*)dst       = *(const short8*)&u[0];
    *(short8*)(dst + 8) = *(const short8*)&u[8];
}

// ---------------- main GEMM + decode ----------------

__global__ __launch_bounds__(256) void detect_gemm(
    const unsigned short* __restrict__ Xb0, const unsigned short* __restrict__ Xb1,
    const unsigned short* __restrict__ Wb0, const unsigned short* __restrict__ Wb1,
    const float* __restrict__ b0, const float* __restrict__ b1,
    float* __restrict__ out)
{
    // 128x128 tile, BK=64; linear LDS (global_load_lds) + XOR-swizzled source/read.
    // smem is reused: during K-loop = sA(16KB)+sB(16KB); epilogue = fp32 [64][130] tile.
    __shared__ __attribute__((aligned(128))) char smem[64 * 130 * 4];
    unsigned short* sA = (unsigned short*)smem;
    unsigned short* sB = sA + 128 * 64;
    float* sOut = (float*)smem;

    // XCD-grouping swizzle: 4160 = 8 * 520 blocks; all 13 N-tiles of an M-tile
    // land on the same XCD, temporally adjacent -> L2 merges partial out lines.
    const int bid   = blockIdx.x;
    const int v     = (bid & 7) * 520 + (bid >> 3);
    const int mtile = v / 13;
    const int ntile = v - mtile * 13;

    const bool lvl1 = (mtile >= 256);
    const unsigned short* __restrict__ Xb = lvl1 ? Xb1 : Xb0;
    const unsigned short* __restrict__ Wb = lvl1 ? Wb1 : Wb0;
    const float* __restrict__ bias = lvl1 ? b1 : b0;
    const int C   = lvl1 ? 512 : 256;
    const int GG  = lvl1 ? 1024 : 4096;
    const int Gsh = lvl1 ? 5 : 6;
    const float sxy     = lvl1 ? 1.1f : 1.2f;
    const float sxy_off = (sxy - 1.0f) * 0.5f;
    const float sf      = lvl1 ? 16.0f : 8.0f;
    const float aw0 = lvl1 ? 30.f : 10.f, aw1v = lvl1 ? 62.f : 16.f, aw2v = lvl1 ? 59.f : 33.f;
    const float ah0 = lvl1 ? 61.f : 13.f, ah1v = lvl1 ? 45.f : 30.f, ah2v = lvl1 ? 119.f : 23.f;

    const int tloc = lvl1 ? (mtile - 256) : mtile;
    const int b  = tloc >> (lvl1 ? 3 : 5);
    const int p0 = (tloc & ((lvl1 ? 8 : 32) - 1)) * 128;
    const int n0 = ntile * 128;

    const unsigned short* __restrict__ Xp = Xb + ((size_t)b * GG + p0) * C;

    const int tid  = threadIdx.x;
    const int lane = tid & 63;
    const int wid  = tid >> 6;
    const int wm = wid >> 1, wn = wid & 1;

    f32x4 acc[4][4];
    #pragma unroll
    for (int i = 0; i < 4; ++i)
        #pragma unroll
        for (int j = 0; j < 4; ++j)
            acc[i][j] = f32x4{0.f, 0.f, 0.f, 0.f};

    // staging geometry (per thread, loop-invariant):
    // issue i: LDS chunk (i*4+wid)*1024 bytes; lane covers chunk + lane*16
    int rowA[4], scolE[4];  // scolE = swizzled column in ELEMENTS
    #pragma unroll
    for (int i = 0; i < 4; ++i) {
        const int off = ((i * 4 + wid) << 10) + (lane << 4);  // byte offset in 16KB tile
        const int row = off >> 7;
        const int col = off & 127;
        rowA[i]  = row;
        scolE[i] = (col ^ ((row & 7) << 4)) >> 1;
    }

    const int lr = lane & 15;
    const int kqb = (lane >> 4) << 4;          // k-quarter byte offset within 64B half-row
    const int swzR = (lr & 7) << 4;            // read-side XOR (row&7 == lr&7 here)

    const int KT = C >> 6;
    for (int kt = 0; kt < KT; ++kt) {
        const int k0 = kt << 6;
        #pragma unroll
        for (int i = 0; i < 4; ++i) {
            const int chunk = ((i * 4 + wid) << 10);
            // A: pixels all valid
            gload16(Xp + (size_t)rowA[i] * C + k0 + scolE[i], (char*)sA + chunk);
            // B: clamp OOB rows (epilogue masks those channels)
            int grow = n0 + rowA[i];
            grow = grow > (OUT_CH - 1) ? (OUT_CH - 1) : grow;
            gload16(Wb + (size_t)grow * C + k0 + scolE[i], (char*)sB + chunk);
        }
        __syncthreads();   // compiler inserts vmcnt(0) drain before barrier
        #pragma unroll
        for (int kk = 0; kk < 2; ++kk) {
            const int cb = (kk << 6) + kqb;
            short8 af[4], bfr[4];
            #pragma unroll
            for (int i = 0; i < 4; ++i) {
                const int ra = wm * 64 + i * 16 + lr;
                af[i]  = *(const short8*)((const char*)sA + ra * 128 + (cb ^ swzR));
                const int rb = wn * 64 + i * 16 + lr;
                bfr[i] = *(const short8*)((const char*)sB + rb * 128 + (cb ^ swzR));
            }
            #pragma unroll
            for (int i = 0; i < 4; ++i)
                #pragma unroll
                for (int j = 0; j < 4; ++j)
                    acc[i][j] = __builtin_amdgcn_mfma_f32_16x16x32_bf16(af[i], bfr[j], acc[i][j], 0, 0, 0);
        }
        __syncthreads();
    }

    // ---- epilogue: bias + decode -> LDS -> coalesced float2 stores ----
    // C/D layout: col(N)=lane&15, row(M)=(lane>>4)*4+reg
    const int rq = (lane >> 4) * 4;
    const int lvloff = lvl1 ? 73728 : 0;

    // per-lane store geometry: this lane owns out-channels oo, oo+1 (fixed).
    // n0 and 2*lane are even and NCHN=86 has even anchor boundaries, so the
    // float2 never straddles an anchor run and is 8B-aligned.
    const int ocol0 = 2 * lane;
    const int oo    = n0 + ocol0;
    const bool ovalid = (oo < OUT_CH);
    const int a_l  = oo / NCHN;
    const int ch_l = oo - a_l * NCHN;
    const size_t sbase = (size_t)b * BPB + ((size_t)(lvloff + a_l * GG)) * NCHN + ch_l;

    #pragma unroll
    for (int h = 0; h < 2; ++h) {
        __syncthreads();
        if (wm == h) {
            #pragma unroll
            for (int j = 0; j < 4; ++j) {
                const int o = n0 + wn * 64 + j * 16 + lr;
                const int col = wn * 64 + j * 16 + lr;
                const int a  = o / NCHN;
                const int ch = o - a * NCHN;
                const float bv = (o < OUT_CH) ? bias[o] : 0.f;
                const int shp  = a / 6;
                const int angi = a - shp * 6;
                const float aw = (shp == 0) ? aw0 : (shp == 1) ? aw1v : aw2v;
                const float ah = (shp == 0) ? ah0 : (shp == 1) ? ah1v : ah2v;
                const float aa = (angi == 0) ? -1.04719755119659775f :
                                 (angi == 1) ? -0.52359877559829887f :
                                 (angi == 2) ?  0.0f :
                                 (angi == 3) ?  0.52359877559829887f :
                                 (angi == 4) ?  1.04719755119659775f :
                                                1.57079632679489662f;
                #pragma unroll
                for (int i = 0; i < 4; ++i) {
                    #pragma unroll
                    for (int r = 0; r < 4; ++r) {
                        const int prow = i * 16 + rq + r;           // 0..63 within half
                        const int p = p0 + h * 64 + prow;
                        const float vv = acc[i][j][r] + bv;
                        float res;
                        if (ch == 0)      res = (sigm(vv) * sxy - sxy_off + (float)(p & ((1 << Gsh) - 1))) * sf;
                        else if (ch == 1) res = (sigm(vv) * sxy - sxy_off + (float)(p >> Gsh)) * sf;
                        else if (ch == 2) res = __expf(vv) * aw;
                        else if (ch == 3) res = __expf(vv) * ah;
                        else if (ch == 4) res = vv + aa;
                        else              res = sigm(vv);
                        sOut[prow * 130 + col] = res;
                    }
                }
            }
        }
        __syncthreads();
        // stream out: wave w owns pixels [w*16, w*16+16) of this half; each lane
        // stores its fixed float2 channel pair -> 512B contiguous per wave-store.
        #pragma unroll
        for (int pp = 0; pp < 16; ++pp) {
            const int prow = (wid << 4) + pp;
            const int p = p0 + h * 64 + prow;
            const float2 vv = *(const float2*)&sOut[prow * 130 + ocol0];
            if (ovalid)
                *(float2*)&out[sbase + (size_t)p * NCHN] = vv;
        }
    }
}

extern "C" void kernel_launch(void* const* d_in, const int* in_sizes, int n_in,
                              void* d_out, int out_size, void* d_ws, size_t ws_size,
                              hipStream_t stream) {
    const float* x0 = (const float*)d_in[0];
    const float* x1 = (const float*)d_in[1];
    const float* W0 = (const float*)d_in[2];
    const float* b0 = (const float*)d_in[3];
    const float* W1 = (const float*)d_in[4];
    const float* b1 = (const float*)d_in[5];
    float* out = (float*)d_out;

    // workspace layout (bytes)
    constexpr size_t XB0_OFF = 0;            // 8*4096*256*2  = 16777216
    constexpr size_t XB1_OFF = 16777216;     // 8*1024*512*2  =  8388608
    constexpr size_t WB0_OFF = 25165824;     // 1548*256*2    =   792576
    constexpr size_t WB1_OFF = 25958400;     // 1548*512*2    =  1585152
    constexpr size_t WS_NEEDED = 27543552;

    unsigned short* Xb0 = (unsigned short*)((char*)d_ws + XB0_OFF);
    unsigned short* Xb1 = (unsigned short*)((char*)d_ws + XB1_OFF);
    unsigned short* Wb0 = (unsigned short*)((char*)d_ws + WB0_OFF);
    unsigned short* Wb1 = (unsigned short*)((char*)d_ws + WB1_OFF);
    (void)WS_NEEDED; (void)ws_size;

    hipLaunchKernelGGL(conv_w_kernel, dim3((99072 + 255) / 256), dim3(256), 0, stream,
                       W0, Wb0, 99072);
    hipLaunchKernelGGL(conv_w_kernel, dim3((198144 + 255) / 256), dim3(256), 0, stream,
                       W1, Wb1, 198144);
    hipLaunchKernelGGL(transpose_x_kernel, dim3(64, 4, 8), dim3(256), 0, stream,
                       x0, Xb0, 256, 4096);
    hipLaunchKernelGGL(transpose_x_kernel, dim3(16, 8, 8), dim3(256), 0, stream,
                       x1, Xb1, 512, 1024);

    hipLaunchKernelGGL(detect_gemm, dim3(4160), dim3(256), 0, stream,
                       Xb0, Xb1, Wb0, Wb1, b0, b1, out);
}

// Round 4
// 218.879 us; speedup vs baseline: 1.8702x; 1.8702x over previous
//
#include <hip/hip_runtime.h>
#include <hip/hip_bf16.h>

// Detect head: prep (fp32->bf16 convert + x transpose) then fused MFMA GEMM + decode.
// R4: 512-thread blocks (8 waves, 64x32 per-wave tile -> 32 acc VGPRs),
//     double-buffered LDS + 2-phase prefetch (issue-before-compute),
//     direct-store epilogue (R2 style), separate __shared__ arrays.

typedef __attribute__((ext_vector_type(8))) short short8;
typedef __attribute__((ext_vector_type(4))) short short4v;
typedef __attribute__((ext_vector_type(4))) float f32x4;
typedef unsigned int u32;

__device__ __forceinline__ unsigned short f2bf(float f) {
    union { float f; unsigned u; } c; c.f = f;
    return (unsigned short)((c.u + 0x7fffu + ((c.u >> 16) & 1u)) >> 16);  // RTNE
}
__device__ __forceinline__ float sigm(float v) {
    return 1.0f / (1.0f + __expf(-v));
}
__device__ __forceinline__ void gload16(const void* g, void* l) {
    __builtin_amdgcn_global_load_lds(
        (const __attribute__((address_space(1))) u32*)g,
        (__attribute__((address_space(3))) u32*)l, 16, 0, 0);
}

#define OUT_CH 1548
#define NCHN   86
#define BPB    7925760   // per-batch output elements = 92160*86

// ---------------- prep kernels ----------------

__global__ void conv_w_kernel(const float* __restrict__ W, unsigned short* __restrict__ Wb, int n4) {
    int i = blockIdx.x * blockDim.x + threadIdx.x;
    if (i >= n4) return;
    const float4 f = ((const float4*)W)[i];
    short4v v;
    v[0] = (short)f2bf(f.x); v[1] = (short)f2bf(f.y);
    v[2] = (short)f2bf(f.z); v[3] = (short)f2bf(f.w);
    ((short4v*)Wb)[i] = v;
}

// x [B][C][GG] fp32 -> Xb [B][GG][C] bf16 (64x64 LDS tile transpose)
__global__ void transpose_x_kernel(const float* __restrict__ X, unsigned short* __restrict__ Xb,
                                   int C, int GG) {
    __shared__ float sT[64][65];
    const int p0 = blockIdx.x * 64;
    const int c0 = blockIdx.y * 64;
    const int b  = blockIdx.z;
    const int tid = threadIdx.x;
    const float* src = X + ((size_t)b * C + c0) * GG + p0;
    const int rc = tid >> 4;           // base c row
    const int cp = (tid & 15) * 4;     // pixel within tile (float4)
    #pragma unroll
    for (int rr = 0; rr < 4; ++rr) {
        const int c = rc + rr * 16;
        const float4 f = *(const float4*)&src[(size_t)c * GG + cp];
        sT[c][cp + 0] = f.x; sT[c][cp + 1] = f.y;
        sT[c][cp + 2] = f.z; sT[c][cp + 3] = f.w;
    }
    __syncthreads();
    const int p  = tid >> 2;           // pixel row 0..63
    const int cg = (tid & 3) * 16;     // channel group
    unsigned short u[16];
    #pragma unroll
    for (int k = 0; k < 16; ++k) u[k] = f2bf(sT[cg + k][p]);
    unsigned short* dst = Xb + ((size_t)b * GG + p0 + p) * C + c0 + cg;
    *(short8*)dst       = *(const short8*)&u[0];
    *(short8*)(dst + 8) = *(const short8*)&u[8];
}

// ---------------- main GEMM + decode ----------------

__global__ __launch_bounds__(512, 4) void detect_gemm(
    const unsigned short* __restrict__ Xb0, const unsigned short* __restrict__ Xb1,
    const unsigned short* __restrict__ Wb0, const unsigned short* __restrict__ Wb1,
    const float* __restrict__ b0, const float* __restrict__ b1,
    float* __restrict__ out)
{
    // 128x128 tile, BK=64, double-buffered linear LDS (+XOR swizzle via source/read).
    __shared__ __attribute__((aligned(128))) unsigned short sA[2][128 * 64];
    __shared__ __attribute__((aligned(128))) unsigned short sB[2][128 * 64];

    // XCD-grouping swizzle: 4160 = 8 * 520 blocks.
    const int bid   = blockIdx.x;
    const int v     = (bid & 7) * 520 + (bid >> 3);
    const int mtile = v / 13;
    const int ntile = v - mtile * 13;

    const bool lvl1 = (mtile >= 256);
    const unsigned short* __restrict__ Xb = lvl1 ? Xb1 : Xb0;
    const unsigned short* __restrict__ Wb = lvl1 ? Wb1 : Wb0;
    const float* __restrict__ bias = lvl1 ? b1 : b0;
    const int C   = lvl1 ? 512 : 256;
    const int GG  = lvl1 ? 1024 : 4096;
    const int Gsh = lvl1 ? 5 : 6;
    const float sxy     = lvl1 ? 1.1f : 1.2f;
    const float sxy_off = (sxy - 1.0f) * 0.5f;
    const float sf      = lvl1 ? 16.0f : 8.0f;
    const float aw0 = lvl1 ? 30.f : 10.f, aw1v = lvl1 ? 62.f : 16.f, aw2v = lvl1 ? 59.f : 33.f;
    const float ah0 = lvl1 ? 61.f : 13.f, ah1v = lvl1 ? 45.f : 30.f, ah2v = lvl1 ? 119.f : 23.f;

    const int tloc = lvl1 ? (mtile - 256) : mtile;
    const int b  = tloc >> (lvl1 ? 3 : 5);
    const int p0 = (tloc & ((lvl1 ? 8 : 32) - 1)) * 128;
    const int n0 = ntile * 128;

    const unsigned short* __restrict__ Xp = Xb + ((size_t)b * GG + p0) * C;

    const int tid  = threadIdx.x;
    const int lane = tid & 63;
    const int wid  = tid >> 6;        // 0..7
    const int wm = wid >> 2;          // 0..1 : pixel half
    const int wn = wid & 3;           // 0..3 : channel quarter

    f32x4 acc[4][2];
    #pragma unroll
    for (int i = 0; i < 4; ++i)
        #pragma unroll
        for (int j = 0; j < 2; ++j)
            acc[i][j] = f32x4{0.f, 0.f, 0.f, 0.f};

    // staging geometry: chunk c = i*8+wid (i=0,1) covers LDS bytes [c*1024, c*1024+1024)
    // = rows c*8..c*8+7 (128B row pitch); lane covers chunk + lane*16 (HW rule).
    // global source is pre-swizzled so the linear LDS image is XOR-swizzled.
    const int rowIn = lane >> 3;                                      // 0..7 row within chunk
    const int scolE = ((((lane & 7) << 4)) ^ (rowIn << 4)) >> 1;      // element col in source

    const int lr   = lane & 15;
    const int kqb  = (lane >> 4) << 4;        // k-quarter byte offset in 64B half-row
    const int swzR = (lr & 7) << 4;           // read-side XOR

    const int KT = C >> 6;

    auto stage = [&](int buf, int kt) {
        const int k0 = kt << 6;
        #pragma unroll
        for (int i = 0; i < 2; ++i) {
            const int c = i * 8 + wid;
            const int row = c * 8 + rowIn;
            char* ldsA = (char*)&sA[buf][0] + (c << 10);
            char* ldsB = (char*)&sB[buf][0] + (c << 10);
            gload16(Xp + (size_t)row * C + k0 + scolE, ldsA);
            int grow = n0 + row;
            grow = grow > (OUT_CH - 1) ? (OUT_CH - 1) : grow;
            gload16(Wb + (size_t)grow * C + k0 + scolE, ldsB);
        }
    };

    auto compute = [&](int buf) {
        #pragma unroll
        for (int kk = 0; kk < 2; ++kk) {
            const int cb = (kk << 6) + kqb;
            short8 af[4], bfr[2];
            #pragma unroll
            for (int i = 0; i < 4; ++i) {
                const int ra = wm * 64 + i * 16 + lr;
                af[i] = *(const short8*)((const char*)&sA[buf][0] + ra * 128 + (cb ^ swzR));
            }
            #pragma unroll
            for (int j = 0; j < 2; ++j) {
                const int rb = wn * 32 + j * 16 + lr;
                bfr[j] = *(const short8*)((const char*)&sB[buf][0] + rb * 128 + (cb ^ swzR));
            }
            #pragma unroll
            for (int i = 0; i < 4; ++i)
                #pragma unroll
                for (int j = 0; j < 2; ++j)
                    acc[i][j] = __builtin_amdgcn_mfma_f32_16x16x32_bf16(af[i], bfr[j], acc[i][j], 0, 0, 0);
        }
    };

    // prologue + 2-phase pipelined K loop (issue next-tile loads BEFORE compute)
    stage(0, 0);
    __syncthreads();
    int cur = 0;
    for (int kt = 0; kt < KT; ++kt) {
        if (kt + 1 < KT) stage(cur ^ 1, kt + 1);
        compute(cur);
        __syncthreads();          // drains this iteration's prefetch loads too
        cur ^= 1;
    }

    // ---- epilogue: bias + decode + direct scatter (64B runs per 16-lane group) ----
    // C/D layout: col(N)=lane&15, row(M)=(lane>>4)*4+reg
    const int rq = (lane >> 4) * 4;
    const int lvloff = lvl1 ? 73728 : 0;
    #pragma unroll
    for (int j = 0; j < 2; ++j) {
        const int o = n0 + wn * 32 + j * 16 + lr;
        if (o >= OUT_CH) continue;
        const int a  = o / NCHN;
        const int ch = o - a * NCHN;
        const float bv = bias[o];
        const int shp  = a / 6;
        const int angi = a - shp * 6;
        const float aw = (shp == 0) ? aw0 : (shp == 1) ? aw1v : aw2v;
        const float ah = (shp == 0) ? ah0 : (shp == 1) ? ah1v : ah2v;
        const float aa = (angi == 0) ? -1.04719755119659775f :
                         (angi == 1) ? -0.52359877559829887f :
                         (angi == 2) ?  0.0f :
                         (angi == 3) ?  0.52359877559829887f :
                         (angi == 4) ?  1.04719755119659775f :
                                        1.57079632679489662f;
        const size_t obase = (size_t)b * BPB + ((size_t)(lvloff + a * GG)) * NCHN + ch;
        #pragma unroll
        for (int i = 0; i < 4; ++i) {
            #pragma unroll
            for (int r = 0; r < 4; ++r) {
                const int p = p0 + wm * 64 + i * 16 + rq + r;
                const float vv = acc[i][j][r] + bv;
                float res;
                if (ch == 0)      res = (sigm(vv) * sxy - sxy_off + (float)(p & ((1 << Gsh) - 1))) * sf;
                else if (ch == 1) res = (sigm(vv) * sxy - sxy_off + (float)(p >> Gsh)) * sf;
                else if (ch == 2) res = __expf(vv) * aw;
                else if (ch == 3) res = __expf(vv) * ah;
                else if (ch == 4) res = vv + aa;
                else              res = sigm(vv);
                out[obase + (size_t)p * NCHN] = res;
            }
        }
    }
}

extern "C" void kernel_launch(void* const* d_in, const int* in_sizes, int n_in,
                              void* d_out, int out_size, void* d_ws, size_t ws_size,
                              hipStream_t stream) {
    const float* x0 = (const float*)d_in[0];
    const float* x1 = (const float*)d_in[1];
    const float* W0 = (const float*)d_in[2];
    const float* b0 = (const float*)d_in[3];
    const float* W1 = (const float*)d_in[4];
    const float* b1 = (const float*)d_in[5];
    float* out = (float*)d_out;

    // workspace layout (bytes)
    constexpr size_t XB0_OFF = 0;            // 8*4096*256*2  = 16777216
    constexpr size_t XB1_OFF = 16777216;     // 8*1024*512*2  =  8388608
    constexpr size_t WB0_OFF = 25165824;     // 1548*256*2    =   792576
    constexpr size_t WB1_OFF = 25958400;     // 1548*512*2    =  1585152

    unsigned short* Xb0 = (unsigned short*)((char*)d_ws + XB0_OFF);
    unsigned short* Xb1 = (unsigned short*)((char*)d_ws + XB1_OFF);
    unsigned short* Wb0 = (unsigned short*)((char*)d_ws + WB0_OFF);
    unsigned short* Wb1 = (unsigned short*)((char*)d_ws + WB1_OFF);

    hipLaunchKernelGGL(conv_w_kernel, dim3((99072 + 255) / 256), dim3(256), 0, stream,
                       W0, Wb0, 99072);
    hipLaunchKernelGGL(conv_w_kernel, dim3((198144 + 255) / 256), dim3(256), 0, stream,
                       W1, Wb1, 198144);
    hipLaunchKernelGGL(transpose_x_kernel, dim3(64, 4, 8), dim3(256), 0, stream,
                       x0, Xb0, 256, 4096);
    hipLaunchKernelGGL(transpose_x_kernel, dim3(16, 8, 8), dim3(256), 0, stream,
                       x1, Xb1, 512, 1024);

    hipLaunchKernelGGL(detect_gemm, dim3(4160), dim3(512), 0, stream,
                       Xb0, Xb1, Wb0, Wb1, b0, b1, out);
}

// Round 5
// 161.743 us; speedup vs baseline: 2.5309x; 1.3532x over previous
//
#include <hip/hip_runtime.h>
#include <hip/hip_bf16.h>

// Detect head: prep (fp32->bf16 convert + x transpose) then fused MFMA GEMM + decode.
// R5: anchor-aligned N-tiling (BN=96 covering one anchor's 86 channels).
//     Each block's output is one fully contiguous 44KB span -> decode into a
//     flat LDS image, stream out with sequential float4 stores (zero write
//     amplification). GEMM core: BM=128, BK=64, dbuf LDS + 2-phase prefetch,
//     global_load_lds w/ XOR swizzle, 8 waves (4m x 2n), acc 2x3.

typedef __attribute__((ext_vector_type(8))) short short8;
typedef __attribute__((ext_vector_type(4))) short short4v;
typedef __attribute__((ext_vector_type(4))) float f32x4;
typedef unsigned int u32;

__device__ __forceinline__ unsigned short f2bf(float f) {
    union { float f; unsigned u; } c; c.f = f;
    return (unsigned short)((c.u + 0x7fffu + ((c.u >> 16) & 1u)) >> 16);  // RTNE
}
__device__ __forceinline__ float sigm(float v) {
    return 1.0f / (1.0f + __expf(-v));
}
__device__ __forceinline__ void gload16(const void* g, void* l) {
    __builtin_amdgcn_global_load_lds(
        (const __attribute__((address_space(1))) u32*)g,
        (__attribute__((address_space(3))) u32*)l, 16, 0, 0);
}

#define OUT_CH 1548
#define NCHN   86
#define BPB    7925760   // per-batch output elements = 92160*86

// ---------------- prep kernels ----------------

__global__ void conv_w_kernel(const float* __restrict__ W, unsigned short* __restrict__ Wb, int n4) {
    int i = blockIdx.x * blockDim.x + threadIdx.x;
    if (i >= n4) return;
    const float4 f = ((const float4*)W)[i];
    short4v v;
    v[0] = (short)f2bf(f.x); v[1] = (short)f2bf(f.y);
    v[2] = (short)f2bf(f.z); v[3] = (short)f2bf(f.w);
    ((short4v*)Wb)[i] = v;
}

// x [B][C][GG] fp32 -> Xb [B][GG][C] bf16 (64x64 LDS tile transpose)
__global__ void transpose_x_kernel(const float* __restrict__ X, unsigned short* __restrict__ Xb,
                                   int C, int GG) {
    __shared__ float sT[64][65];
    const int p0 = blockIdx.x * 64;
    const int c0 = blockIdx.y * 64;
    const int b  = blockIdx.z;
    const int tid = threadIdx.x;
    const float* src = X + ((size_t)b * C + c0) * GG + p0;
    const int rc = tid >> 4;           // base c row
    const int cp = (tid & 15) * 4;     // pixel within tile (float4)
    #pragma unroll
    for (int rr = 0; rr < 4; ++rr) {
        const int c = rc + rr * 16;
        const float4 f = *(const float4*)&src[(size_t)c * GG + cp];
        sT[c][cp + 0] = f.x; sT[c][cp + 1] = f.y;
        sT[c][cp + 2] = f.z; sT[c][cp + 3] = f.w;
    }
    __syncthreads();
    const int p  = tid >> 2;           // pixel row 0..63
    const int cg = (tid & 3) * 16;     // channel group
    unsigned short u[16];
    #pragma unroll
    for (int k = 0; k < 16; ++k) u[k] = f2bf(sT[cg + k][p]);
    unsigned short* dst = Xb + ((size_t)b * GG + p0 + p) * C + c0 + cg;
    *(short8*)dst       = *(const short8*)&u[0];
    *(short8*)(dst + 8) = *(const short8*)&u[8];
}

// ---------------- main GEMM + decode ----------------

__global__ __launch_bounds__(512, 4) void detect_gemm(
    const unsigned short* __restrict__ Xb0, const unsigned short* __restrict__ Xb1,
    const unsigned short* __restrict__ Wb0, const unsigned short* __restrict__ Wb1,
    const float* __restrict__ b0, const float* __restrict__ b1,
    float* __restrict__ out)
{
    // LDS: GEMM phase uses sA dbuf (2x16KB) + sB dbuf (2x12KB) = 56KB.
    // Epilogue reuses the same memory as a flat [128*86] fp32 image (43KB).
    __shared__ __attribute__((aligned(128))) char smem[57344];
    unsigned short* sAbase = (unsigned short*)smem;               // 2 x 8192 elems
    unsigned short* sBbase = (unsigned short*)(smem + 32768);     // 2 x 6144 elems
    float* sOutF = (float*)smem;

    // XCD swizzle: 5760 = 8 * 720. Within an XCD consecutive blocks are
    // consecutive mtiles of the same anchor -> adjacent output spans.
    const int bid = blockIdx.x;
    const int v   = (bid & 7) * 720 + (bid >> 3);
    const int a   = v / 320;          // anchor 0..17
    const int mt  = v - a * 320;      // mtile 0..319

    const bool lvl1 = (mt >= 256);
    const unsigned short* __restrict__ Xb = lvl1 ? Xb1 : Xb0;
    const unsigned short* __restrict__ Wb = lvl1 ? Wb1 : Wb0;
    const float* __restrict__ biasA = (lvl1 ? b1 : b0) + a * NCHN;
    const int C   = lvl1 ? 512 : 256;
    const int GG  = lvl1 ? 1024 : 4096;
    const int Gsh = lvl1 ? 5 : 6;
    const float sxy     = lvl1 ? 1.1f : 1.2f;
    const float sxy_off = (sxy - 1.0f) * 0.5f;
    const float sf      = lvl1 ? 16.0f : 8.0f;
    // anchor constants are block-uniform now
    const int shp  = a / 6;
    const int angi = a - shp * 6;
    const float aw = lvl1 ? ((shp == 0) ? 30.f : (shp == 1) ? 62.f : 59.f)
                          : ((shp == 0) ? 10.f : (shp == 1) ? 16.f : 33.f);
    const float ah = lvl1 ? ((shp == 0) ? 61.f : (shp == 1) ? 45.f : 119.f)
                          : ((shp == 0) ? 13.f : (shp == 1) ? 30.f : 23.f);
    const float aa = (angi == 0) ? -1.04719755119659775f :
                     (angi == 1) ? -0.52359877559829887f :
                     (angi == 2) ?  0.0f :
                     (angi == 3) ?  0.52359877559829887f :
                     (angi == 4) ?  1.04719755119659775f :
                                    1.57079632679489662f;

    const int tloc = lvl1 ? (mt - 256) : mt;
    const int b  = tloc >> (lvl1 ? 3 : 5);
    const int p0 = (tloc & ((lvl1 ? 8 : 32) - 1)) * 128;

    const unsigned short* __restrict__ Xp = Xb + ((size_t)b * GG + p0) * C;
    const unsigned short* __restrict__ Wp = Wb;   // rows indexed a*86 + n (clamped)

    const int tid  = threadIdx.x;
    const int lane = tid & 63;
    const int wid  = tid >> 6;        // 0..7
    const int wm = wid >> 1;          // 0..3 : 32-pixel slice
    const int wn = wid & 1;           // 0..1 : 48-channel half

    f32x4 acc[2][3];
    #pragma unroll
    for (int i = 0; i < 2; ++i)
        #pragma unroll
        for (int j = 0; j < 3; ++j)
            acc[i][j] = f32x4{0.f, 0.f, 0.f, 0.f};

    // staging geometry: per issue, wave wid covers 8 rows (1KB) of the tile;
    // lane covers base + lane*16 (HW rule). Source col pre-swizzled.
    const int rowIn = lane >> 3;                                  // 0..7
    const int scolE = ((((lane & 7) << 4)) ^ (rowIn << 4)) >> 1;  // element col in source

    const int lr   = lane & 15;
    const int kqb  = (lane >> 4) << 4;        // k-quarter byte offset in 64B half-row
    const int swzR = (lr & 7) << 4;           // read-side XOR

    const int KT = C >> 6;

    auto stage = [&](int bufsel, int kt) {
        const int k0 = kt << 6;
        unsigned short* sA = sAbase + bufsel * 8192;
        unsigned short* sB = sBbase + bufsel * 6144;
        // A: 16KB = 2 issues x 8KB
        #pragma unroll
        for (int i = 0; i < 2; ++i) {
            const int row = i * 64 + wid * 8 + rowIn;
            gload16(Xp + (size_t)row * C + k0 + scolE,
                    (char*)sA + i * 8192 + wid * 1024);
        }
        // B: 12KB = 8KB (all waves) + 4KB (waves 0-3)
        {
            const int n = wid * 8 + rowIn;
            int grow = a * NCHN + n;
            grow = grow > (OUT_CH - 1) ? (OUT_CH - 1) : grow;
            gload16(Wp + (size_t)grow * C + k0 + scolE,
                    (char*)sB + wid * 1024);
        }
        if (wid < 4) {
            const int n = 64 + wid * 8 + rowIn;
            int grow = a * NCHN + n;
            grow = grow > (OUT_CH - 1) ? (OUT_CH - 1) : grow;
            gload16(Wp + (size_t)grow * C + k0 + scolE,
                    (char*)sB + 8192 + wid * 1024);
        }
    };

    auto compute = [&](int bufsel) {
        const unsigned short* sA = sAbase + bufsel * 8192;
        const unsigned short* sB = sBbase + bufsel * 6144;
        #pragma unroll
        for (int kk = 0; kk < 2; ++kk) {
            const int cb = (kk << 6) + kqb;
            short8 af[2], bfr[3];
            #pragma unroll
            for (int i = 0; i < 2; ++i) {
                const int ra = wm * 32 + i * 16 + lr;
                af[i] = *(const short8*)((const char*)sA + ra * 128 + (cb ^ swzR));
            }
            #pragma unroll
            for (int j = 0; j < 3; ++j) {
                const int rb = wn * 48 + j * 16 + lr;
                bfr[j] = *(const short8*)((const char*)sB + rb * 128 + (cb ^ swzR));
            }
            #pragma unroll
            for (int i = 0; i < 2; ++i)
                #pragma unroll
                for (int j = 0; j < 3; ++j)
                    acc[i][j] = __builtin_amdgcn_mfma_f32_16x16x32_bf16(af[i], bfr[j], acc[i][j], 0, 0, 0);
        }
    };

    // prologue + 2-phase pipelined K loop (issue next-tile loads BEFORE compute)
    stage(0, 0);
    __syncthreads();
    int cur = 0;
    for (int kt = 0; kt < KT; ++kt) {
        if (kt + 1 < KT) stage(cur ^ 1, kt + 1);
        compute(cur);
        __syncthreads();          // drains this iteration's prefetch loads too
        cur ^= 1;
    }

    // ---- epilogue: decode into flat LDS image [128 px][86 ch], then stream out ----
    // C/D layout: col(N)=lane&15, row(M)=(lane>>4)*4+reg
    const int rq = (lane >> 4) * 4;
    const int lvloff = lvl1 ? 73728 : 0;

    #pragma unroll
    for (int j = 0; j < 3; ++j) {
        const int ch = wn * 48 + j * 16 + lr;
        if (ch < NCHN) {
            const float bv = biasA[ch];
            #pragma unroll
            for (int i = 0; i < 2; ++i) {
                #pragma unroll
                for (int r = 0; r < 4; ++r) {
                    const int px = wm * 32 + i * 16 + rq + r;   // 0..127
                    const int p  = p0 + px;                     // pixel in level grid
                    const float vv = acc[i][j][r] + bv;
                    float res;
                    if (ch == 0)      res = (sigm(vv) * sxy - sxy_off + (float)(p & ((1 << Gsh) - 1))) * sf;
                    else if (ch == 1) res = (sigm(vv) * sxy - sxy_off + (float)(p >> Gsh)) * sf;
                    else if (ch == 2) res = __expf(vv) * aw;
                    else if (ch == 3) res = __expf(vv) * ah;
                    else if (ch == 4) res = vv + aa;
                    else              res = sigm(vv);
                    sOutF[px * NCHN + ch] = res;
                }
            }
        }
    }
    __syncthreads();

    // stream out: block span = 128*86 dwords, contiguous & 16B-aligned.
    const size_t spanDw = (size_t)b * BPB + ((size_t)(lvloff + a * GG + p0)) * NCHN;
    #pragma unroll
    for (int d0 = 0; d0 < 128 * NCHN; d0 += 2048) {
        const int d = d0 + tid * 4;
        if (d < 128 * NCHN) {
            const float4 vv = *(const float4*)&sOutF[d];
            *(float4*)&out[spanDw + d] = vv;
        }
    }
}

extern "C" void kernel_launch(void* const* d_in, const int* in_sizes, int n_in,
                              void* d_out, int out_size, void* d_ws, size_t ws_size,
                              hipStream_t stream) {
    const float* x0 = (const float*)d_in[0];
    const float* x1 = (const float*)d_in[1];
    const float* W0 = (const float*)d_in[2];
    const float* b0 = (const float*)d_in[3];
    const float* W1 = (const float*)d_in[4];
    const float* b1 = (const float*)d_in[5];
    float* out = (float*)d_out;

    // workspace layout (bytes)
    constexpr size_t XB0_OFF = 0;            // 8*4096*256*2  = 16777216
    constexpr size_t XB1_OFF = 16777216;     // 8*1024*512*2  =  8388608
    constexpr size_t WB0_OFF = 25165824;     // 1548*256*2    =   792576
    constexpr size_t WB1_OFF = 25958400;     // 1548*512*2    =  1585152

    unsigned short* Xb0 = (unsigned short*)((char*)d_ws + XB0_OFF);
    unsigned short* Xb1 = (unsigned short*)((char*)d_ws + XB1_OFF);
    unsigned short* Wb0 = (unsigned short*)((char*)d_ws + WB0_OFF);
    unsigned short* Wb1 = (unsigned short*)((char*)d_ws + WB1_OFF);

    hipLaunchKernelGGL(conv_w_kernel, dim3((99072 + 255) / 256), dim3(256), 0, stream,
                       W0, Wb0, 99072);
    hipLaunchKernelGGL(conv_w_kernel, dim3((198144 + 255) / 256), dim3(256), 0, stream,
                       W1, Wb1, 198144);
    hipLaunchKernelGGL(transpose_x_kernel, dim3(64, 4, 8), dim3(256), 0, stream,
                       x0, Xb0, 256, 4096);
    hipLaunchKernelGGL(transpose_x_kernel, dim3(16, 8, 8), dim3(256), 0, stream,
                       x1, Xb1, 512, 1024);

    // 18 anchors x 320 mtiles = 5760 blocks
    hipLaunchKernelGGL(detect_gemm, dim3(5760), dim3(512), 0, stream,
                       Xb0, Xb1, Wb0, Wb1, b0, b1, out);
}

// Round 6
// 161.065 us; speedup vs baseline: 2.5416x; 1.0042x over previous
//
#include <hip/hip_runtime.h>
#include <hip/hip_bf16.h>

// Detect head: prep (fp32->bf16 convert + x transpose) then fused MFMA GEMM + decode.
// R6: BM=64 x BN=96 (anchor-aligned), BK=64, dbuf + 2-phase prefetch, LDS 40KB
//     -> 4 blocks/CU (32 waves/CU). XCD swizzle groups the 18 anchors of one
//     mtile (A-tile L2 reuse). Epilogue: decode -> 22KB LDS image -> contiguous
//     float4 stream (zero write amplification). 11520 blocks.

typedef __attribute__((ext_vector_type(8))) short short8;
typedef __attribute__((ext_vector_type(4))) short short4v;
typedef __attribute__((ext_vector_type(4))) float f32x4;
typedef unsigned int u32;

__device__ __forceinline__ unsigned short f2bf(float f) {
    union { float f; unsigned u; } c; c.f = f;
    return (unsigned short)((c.u + 0x7fffu + ((c.u >> 16) & 1u)) >> 16);  // RTNE
}
__device__ __forceinline__ float sigm(float v) {
    return 1.0f / (1.0f + __expf(-v));
}
__device__ __forceinline__ void gload16(const void* g, void* l) {
    __builtin_amdgcn_global_load_lds(
        (const __attribute__((address_space(1))) u32*)g,
        (__attribute__((address_space(3))) u32*)l, 16, 0, 0);
}

#define OUT_CH 1548
#define NCHN   86
#define BPB    7925760   // per-batch output elements = 92160*86

// ---------------- prep kernels ----------------

// both W tensors in one launch: i < 99072 -> W0, else W1
__global__ void conv_w_kernel(const float* __restrict__ W0, unsigned short* __restrict__ Wb0,
                              const float* __restrict__ W1, unsigned short* __restrict__ Wb1) {
    int i = blockIdx.x * blockDim.x + threadIdx.x;
    if (i >= 297216) return;
    const float* W = W0;
    unsigned short* Wb = Wb0;
    if (i >= 99072) { W = W1; Wb = Wb1; i -= 99072; }
    const float4 f = ((const float4*)W)[i];
    short4v v;
    v[0] = (short)f2bf(f.x); v[1] = (short)f2bf(f.y);
    v[2] = (short)f2bf(f.z); v[3] = (short)f2bf(f.w);
    ((short4v*)Wb)[i] = v;
}

// x [B][C][GG] fp32 -> Xb [B][GG][C] bf16 (64x64 LDS tile transpose)
__global__ void transpose_x_kernel(const float* __restrict__ X, unsigned short* __restrict__ Xb,
                                   int C, int GG) {
    __shared__ float sT[64][65];
    const int p0 = blockIdx.x * 64;
    const int c0 = blockIdx.y * 64;
    const int b  = blockIdx.z;
    const int tid = threadIdx.x;
    const float* src = X + ((size_t)b * C + c0) * GG + p0;
    const int rc = tid >> 4;           // base c row
    const int cp = (tid & 15) * 4;     // pixel within tile (float4)
    #pragma unroll
    for (int rr = 0; rr < 4; ++rr) {
        const int c = rc + rr * 16;
        const float4 f = *(const float4*)&src[(size_t)c * GG + cp];
        sT[c][cp + 0] = f.x; sT[c][cp + 1] = f.y;
        sT[c][cp + 2] = f.z; sT[c][cp + 3] = f.w;
    }
    __syncthreads();
    const int p  = tid >> 2;           // pixel row 0..63
    const int cg = (tid & 3) * 16;     // channel group
    unsigned short u[16];
    #pragma unroll
    for (int k = 0; k < 16; ++k) u[k] = f2bf(sT[cg + k][p]);
    unsigned short* dst = Xb + ((size_t)b * GG + p0 + p) * C + c0 + cg;
    *(short8*)dst       = *(const short8*)&u[0];
    *(short8*)(dst + 8) = *(const short8*)&u[8];
}

// ---------------- main GEMM + decode ----------------

__global__ __launch_bounds__(512, 8) void detect_gemm(
    const unsigned short* __restrict__ Xb0, const unsigned short* __restrict__ Xb1,
    const unsigned short* __restrict__ Wb0, const unsigned short* __restrict__ Wb1,
    const float* __restrict__ b0, const float* __restrict__ b1,
    float* __restrict__ out)
{
    // LDS 40KB total: sA dbuf 2x8KB + sB dbuf 2x12KB; epilogue reuses as
    // flat [64*86] fp32 image (22KB). 160/40 = 4 blocks/CU.
    __shared__ __attribute__((aligned(128))) char smem[40960];
    unsigned short* sAbase = (unsigned short*)smem;               // 2 x 4096 elems
    unsigned short* sBbase = (unsigned short*)(smem + 16384);     // 2 x 6144 elems
    float* sOutF = (float*)smem;

    // XCD swizzle: 11520 = 8 * 1440. Consecutive v within an XCD share the
    // same mtile across 18 anchors -> A-tile fetched once, L2-hit 17x.
    const int bid = blockIdx.x;
    const int v   = (bid & 7) * 1440 + (bid >> 3);
    const int mt  = v / 18;           // mtile 0..639
    const int a   = v - mt * 18;      // anchor 0..17

    const bool lvl1 = (mt >= 512);
    const unsigned short* __restrict__ Xb = lvl1 ? Xb1 : Xb0;
    const unsigned short* __restrict__ Wb = lvl1 ? Wb1 : Wb0;
    const float* __restrict__ biasA = (lvl1 ? b1 : b0) + a * NCHN;
    const int C   = lvl1 ? 512 : 256;
    const int GG  = lvl1 ? 1024 : 4096;
    const int Gsh = lvl1 ? 5 : 6;
    const float sxy     = lvl1 ? 1.1f : 1.2f;
    const float sxy_off = (sxy - 1.0f) * 0.5f;
    const float sf      = lvl1 ? 16.0f : 8.0f;
    // anchor constants (block-uniform)
    const int shp  = a / 6;
    const int angi = a - shp * 6;
    const float aw = lvl1 ? ((shp == 0) ? 30.f : (shp == 1) ? 62.f : 59.f)
                          : ((shp == 0) ? 10.f : (shp == 1) ? 16.f : 33.f);
    const float ah = lvl1 ? ((shp == 0) ? 61.f : (shp == 1) ? 45.f : 119.f)
                          : ((shp == 0) ? 13.f : (shp == 1) ? 30.f : 23.f);
    const float aa = (angi == 0) ? -1.04719755119659775f :
                     (angi == 1) ? -0.52359877559829887f :
                     (angi == 2) ?  0.0f :
                     (angi == 3) ?  0.52359877559829887f :
                     (angi == 4) ?  1.04719755119659775f :
                                    1.57079632679489662f;

    const int tloc = lvl1 ? (mt - 512) : mt;
    const int b  = tloc >> (lvl1 ? 4 : 6);               // tiles/img: 16 / 64
    const int p0 = (tloc & ((lvl1 ? 16 : 64) - 1)) * 64; // pixel offset

    const unsigned short* __restrict__ Xp = Xb + ((size_t)b * GG + p0) * C;

    const int tid  = threadIdx.x;
    const int lane = tid & 63;
    const int wid  = tid >> 6;        // 0..7
    const int wm = wid >> 1;          // 0..3 : 16-pixel slice
    const int wn = wid & 1;           // 0..1 : 48-channel half

    f32x4 acc[3];
    #pragma unroll
    for (int j = 0; j < 3; ++j)
        acc[j] = f32x4{0.f, 0.f, 0.f, 0.f};

    // staging geometry: each wave-issue covers 8 rows (1KB, 128B row pitch);
    // lane covers base + lane*16 (HW rule). Source col pre-swizzled so the
    // linear LDS image is XOR-swizzled.
    const int rowIn = lane >> 3;                                  // 0..7
    const int scolE = ((((lane & 7) << 4)) ^ (rowIn << 4)) >> 1;  // element col in source

    const int lr   = lane & 15;
    const int kqb  = (lane >> 4) << 4;        // k-quarter byte offset in 64B half-row
    const int swzR = (lr & 7) << 4;           // read-side XOR

    const int KT = C >> 6;

    auto stage = [&](int bufsel, int kt) {
        const int k0 = kt << 6;
        unsigned short* sA = sAbase + bufsel * 4096;
        unsigned short* sB = sBbase + bufsel * 6144;
        // A: 8KB, one issue per wave (rows wid*8 .. wid*8+7)
        {
            const int row = wid * 8 + rowIn;
            gload16(Xp + (size_t)row * C + k0 + scolE, (char*)sA + wid * 1024);
        }
        // B: 12KB = 8KB (all waves) + 4KB (waves 0-3)
        {
            const int n = wid * 8 + rowIn;
            int grow = a * NCHN + n;
            grow = grow > (OUT_CH - 1) ? (OUT_CH - 1) : grow;
            gload16(Wb + (size_t)grow * C + k0 + scolE, (char*)sB + wid * 1024);
        }
        if (wid < 4) {
            const int n = 64 + wid * 8 + rowIn;
            int grow = a * NCHN + n;
            grow = grow > (OUT_CH - 1) ? (OUT_CH - 1) : grow;
            gload16(Wb + (size_t)grow * C + k0 + scolE, (char*)sB + 8192 + wid * 1024);
        }
    };

    auto compute = [&](int bufsel) {
        const unsigned short* sA = sAbase + bufsel * 4096;
        const unsigned short* sB = sBbase + bufsel * 6144;
        #pragma unroll
        for (int kk = 0; kk < 2; ++kk) {
            const int cb = (kk << 6) + kqb;
            const int ra = wm * 16 + lr;
            const short8 af = *(const short8*)((const char*)sA + ra * 128 + (cb ^ swzR));
            short8 bfr[3];
            #pragma unroll
            for (int j = 0; j < 3; ++j) {
                const int rb = wn * 48 + j * 16 + lr;
                bfr[j] = *(const short8*)((const char*)sB + rb * 128 + (cb ^ swzR));
            }
            #pragma unroll
            for (int j = 0; j < 3; ++j)
                acc[j] = __builtin_amdgcn_mfma_f32_16x16x32_bf16(af, bfr[j], acc[j], 0, 0, 0);
        }
    };

    // prologue + 2-phase pipelined K loop (issue next-tile loads BEFORE compute)
    stage(0, 0);
    __syncthreads();
    int cur = 0;
    for (int kt = 0; kt < KT; ++kt) {
        if (kt + 1 < KT) stage(cur ^ 1, kt + 1);
        compute(cur);
        __syncthreads();          // drains this iteration's prefetch loads too
        cur ^= 1;
    }

    // ---- epilogue: decode into flat LDS image [64 px][86 ch], then stream out ----
    // C/D layout: col(N)=lane&15, row(M)=(lane>>4)*4+reg
    const int rq = (lane >> 4) * 4;
    const int lvloff = lvl1 ? 73728 : 0;

    #pragma unroll
    for (int j = 0; j < 3; ++j) {
        const int ch = wn * 48 + j * 16 + lr;
        if (ch < NCHN) {
            const float bv = biasA[ch];
            #pragma unroll
            for (int r = 0; r < 4; ++r) {
                const int px = wm * 16 + rq + r;            // 0..63
                const int p  = p0 + px;                     // pixel in level grid
                const float vv = acc[j][r] + bv;
                float res;
                if (ch == 0)      res = (sigm(vv) * sxy - sxy_off + (float)(p & ((1 << Gsh) - 1))) * sf;
                else if (ch == 1) res = (sigm(vv) * sxy - sxy_off + (float)(p >> Gsh)) * sf;
                else if (ch == 2) res = __expf(vv) * aw;
                else if (ch == 3) res = __expf(vv) * ah;
                else if (ch == 4) res = vv + aa;
                else              res = sigm(vv);
                sOutF[px * NCHN + ch] = res;
            }
        }
    }
    __syncthreads();

    // stream out: block span = 64*86 = 5504 dwords, contiguous & 16B-aligned.
    const size_t spanDw = (size_t)b * BPB + ((size_t)(lvloff + a * GG + p0)) * NCHN;
    #pragma unroll
    for (int k = 0; k < 3; ++k) {
        const int f4 = tid + k * 512;       // float4 index, 1376 total
        if (f4 < 1376) {
            const float4 vv = *(const float4*)&sOutF[f4 * 4];
            *(float4*)&out[spanDw + f4 * 4] = vv;
        }
    }
}

extern "C" void kernel_launch(void* const* d_in, const int* in_sizes, int n_in,
                              void* d_out, int out_size, void* d_ws, size_t ws_size,
                              hipStream_t stream) {
    const float* x0 = (const float*)d_in[0];
    const float* x1 = (const float*)d_in[1];
    const float* W0 = (const float*)d_in[2];
    const float* b0 = (const float*)d_in[3];
    const float* W1 = (const float*)d_in[4];
    const float* b1 = (const float*)d_in[5];
    float* out = (float*)d_out;

    // workspace layout (bytes)
    constexpr size_t XB0_OFF = 0;            // 8*4096*256*2  = 16777216
    constexpr size_t XB1_OFF = 16777216;     // 8*1024*512*2  =  8388608
    constexpr size_t WB0_OFF = 25165824;     // 1548*256*2    =   792576
    constexpr size_t WB1_OFF = 25958400;     // 1548*512*2    =  1585152

    unsigned short* Xb0 = (unsigned short*)((char*)d_ws + XB0_OFF);
    unsigned short* Xb1 = (unsigned short*)((char*)d_ws + XB1_OFF);
    unsigned short* Wb0 = (unsigned short*)((char*)d_ws + WB0_OFF);
    unsigned short* Wb1 = (unsigned short*)((char*)d_ws + WB1_OFF);

    hipLaunchKernelGGL(conv_w_kernel, dim3((297216 + 255) / 256), dim3(256), 0, stream,
                       W0, Wb0, W1, Wb1);
    hipLaunchKernelGGL(transpose_x_kernel, dim3(64, 4, 8), dim3(256), 0, stream,
                       x0, Xb0, 256, 4096);
    hipLaunchKernelGGL(transpose_x_kernel, dim3(16, 8, 8), dim3(256), 0, stream,
                       x1, Xb1, 512, 1024);

    // 640 mtiles (512 lvl0 + 128 lvl1) x 18 anchors = 11520 blocks
    hipLaunchKernelGGL(detect_gemm, dim3(11520), dim3(512), 0, stream,
                       Xb0, Xb1, Wb0, Wb1, b0, b1, out);
}

// Round 8
// 149.516 us; speedup vs baseline: 2.7379x; 1.0772x over previous
//
#include <hip/hip_runtime.h>
#include <hip/hip_bf16.h>

// Detect head: prep (fp32->bf16 convert + x transpose) then fused MFMA GEMM + decode.
// R8 = R6 + non-temporal output stores (L2-bypass streaming writes), fixed to use
//     ext_vector_type for __builtin_nontemporal_store (HIP float4 is a struct).
//     R6: BM=64 x BN=96 (anchor-aligned), BK=64, dbuf + 2-phase prefetch, 40KB LDS
//     -> 4 blocks/CU. XCD swizzle groups 18 anchors of one mtile (A-tile L2 reuse).
//     Epilogue: decode -> LDS image -> contiguous float4 nt-stores.

typedef __attribute__((ext_vector_type(8))) short short8;
typedef __attribute__((ext_vector_type(4))) short short4v;
typedef __attribute__((ext_vector_type(4))) float f32x4;
typedef unsigned int u32;

__device__ __forceinline__ unsigned short f2bf(float f) {
    union { float f; unsigned u; } c; c.f = f;
    return (unsigned short)((c.u + 0x7fffu + ((c.u >> 16) & 1u)) >> 16);  // RTNE
}
__device__ __forceinline__ float sigm(float v) {
    return 1.0f / (1.0f + __expf(-v));
}
__device__ __forceinline__ void gload16(const void* g, void* l) {
    __builtin_amdgcn_global_load_lds(
        (const __attribute__((address_space(1))) u32*)g,
        (__attribute__((address_space(3))) u32*)l, 16, 0, 0);
}

#define OUT_CH 1548
#define NCHN   86
#define BPB    7925760   // per-batch output elements = 92160*86

// ---------------- prep kernels ----------------

// both W tensors in one launch: i < 99072 -> W0, else W1
__global__ void conv_w_kernel(const float* __restrict__ W0, unsigned short* __restrict__ Wb0,
                              const float* __restrict__ W1, unsigned short* __restrict__ Wb1) {
    int i = blockIdx.x * blockDim.x + threadIdx.x;
    if (i >= 297216) return;
    const float* W = W0;
    unsigned short* Wb = Wb0;
    if (i >= 99072) { W = W1; Wb = Wb1; i -= 99072; }
    const float4 f = ((const float4*)W)[i];
    short4v v;
    v[0] = (short)f2bf(f.x); v[1] = (short)f2bf(f.y);
    v[2] = (short)f2bf(f.z); v[3] = (short)f2bf(f.w);
    ((short4v*)Wb)[i] = v;
}

// x [B][C][GG] fp32 -> Xb [B][GG][C] bf16 (64x64 LDS tile transpose)
__global__ void transpose_x_kernel(const float* __restrict__ X, unsigned short* __restrict__ Xb,
                                   int C, int GG) {
    __shared__ float sT[64][65];
    const int p0 = blockIdx.x * 64;
    const int c0 = blockIdx.y * 64;
    const int b  = blockIdx.z;
    const int tid = threadIdx.x;
    const float* src = X + ((size_t)b * C + c0) * GG + p0;
    const int rc = tid >> 4;           // base c row
    const int cp = (tid & 15) * 4;     // pixel within tile (float4)
    #pragma unroll
    for (int rr = 0; rr < 4; ++rr) {
        const int c = rc + rr * 16;
        const float4 f = *(const float4*)&src[(size_t)c * GG + cp];
        sT[c][cp + 0] = f.x; sT[c][cp + 1] = f.y;
        sT[c][cp + 2] = f.z; sT[c][cp + 3] = f.w;
    }
    __syncthreads();
    const int p  = tid >> 2;           // pixel row 0..63
    const int cg = (tid & 3) * 16;     // channel group
    unsigned short u[16];
    #pragma unroll
    for (int k = 0; k < 16; ++k) u[k] = f2bf(sT[cg + k][p]);
    unsigned short* dst = Xb + ((size_t)b * GG + p0 + p) * C + c0 + cg;
    *(short8*)dst       = *(const short8*)&u[0];
    *(short8*)(dst + 8) = *(const short8*)&u[8];
}

// ---------------- main GEMM + decode ----------------

__global__ __launch_bounds__(512, 8) void detect_gemm(
    const unsigned short* __restrict__ Xb0, const unsigned short* __restrict__ Xb1,
    const unsigned short* __restrict__ Wb0, const unsigned short* __restrict__ Wb1,
    const float* __restrict__ b0, const float* __restrict__ b1,
    float* __restrict__ out)
{
    // LDS 40KB total: sA dbuf 2x8KB + sB dbuf 2x12KB; epilogue reuses as
    // flat [64*86] fp32 image (22KB). 160/40 = 4 blocks/CU.
    __shared__ __attribute__((aligned(128))) char smem[40960];
    unsigned short* sAbase = (unsigned short*)smem;               // 2 x 4096 elems
    unsigned short* sBbase = (unsigned short*)(smem + 16384);     // 2 x 6144 elems
    float* sOutF = (float*)smem;

    // XCD swizzle: 11520 = 8 * 1440. Consecutive v within an XCD share the
    // same mtile across 18 anchors -> A-tile fetched once, L2-hit 17x.
    const int bid = blockIdx.x;
    const int v   = (bid & 7) * 1440 + (bid >> 3);
    const int mt  = v / 18;           // mtile 0..639
    const int a   = v - mt * 18;      // anchor 0..17

    const bool lvl1 = (mt >= 512);
    const unsigned short* __restrict__ Xb = lvl1 ? Xb1 : Xb0;
    const unsigned short* __restrict__ Wb = lvl1 ? Wb1 : Wb0;
    const float* __restrict__ biasA = (lvl1 ? b1 : b0) + a * NCHN;
    const int C   = lvl1 ? 512 : 256;
    const int GG  = lvl1 ? 1024 : 4096;
    const int Gsh = lvl1 ? 5 : 6;
    const float sxy     = lvl1 ? 1.1f : 1.2f;
    const float sxy_off = (sxy - 1.0f) * 0.5f;
    const float sf      = lvl1 ? 16.0f : 8.0f;
    // anchor constants (block-uniform)
    const int shp  = a / 6;
    const int angi = a - shp * 6;
    const float aw = lvl1 ? ((shp == 0) ? 30.f : (shp == 1) ? 62.f : 59.f)
                          : ((shp == 0) ? 10.f : (shp == 1) ? 16.f : 33.f);
    const float ah = lvl1 ? ((shp == 0) ? 61.f : (shp == 1) ? 45.f : 119.f)
                          : ((shp == 0) ? 13.f : (shp == 1) ? 30.f : 23.f);
    const float aa = (angi == 0) ? -1.04719755119659775f :
                     (angi == 1) ? -0.52359877559829887f :
                     (angi == 2) ?  0.0f :
                     (angi == 3) ?  0.52359877559829887f :
                     (angi == 4) ?  1.04719755119659775f :
                                    1.57079632679489662f;

    const int tloc = lvl1 ? (mt - 512) : mt;
    const int b  = tloc >> (lvl1 ? 4 : 6);               // tiles/img: 16 / 64
    const int p0 = (tloc & ((lvl1 ? 16 : 64) - 1)) * 64; // pixel offset

    const unsigned short* __restrict__ Xp = Xb + ((size_t)b * GG + p0) * C;

    const int tid  = threadIdx.x;
    const int lane = tid & 63;
    const int wid  = tid >> 6;        // 0..7
    const int wm = wid >> 1;          // 0..3 : 16-pixel slice
    const int wn = wid & 1;           // 0..1 : 48-channel half

    f32x4 acc[3];
    #pragma unroll
    for (int j = 0; j < 3; ++j)
        acc[j] = f32x4{0.f, 0.f, 0.f, 0.f};

    // staging geometry: each wave-issue covers 8 rows (1KB, 128B row pitch);
    // lane covers base + lane*16 (HW rule). Source col pre-swizzled so the
    // linear LDS image is XOR-swizzled.
    const int rowIn = lane >> 3;                                  // 0..7
    const int scolE = ((((lane & 7) << 4)) ^ (rowIn << 4)) >> 1;  // element col in source

    const int lr   = lane & 15;
    const int kqb  = (lane >> 4) << 4;        // k-quarter byte offset in 64B half-row
    const int swzR = (lr & 7) << 4;           // read-side XOR

    const int KT = C >> 6;

    auto stage = [&](int bufsel, int kt) {
        const int k0 = kt << 6;
        unsigned short* sA = sAbase + bufsel * 4096;
        unsigned short* sB = sBbase + bufsel * 6144;
        // A: 8KB, one issue per wave (rows wid*8 .. wid*8+7)
        {
            const int row = wid * 8 + rowIn;
            gload16(Xp + (size_t)row * C + k0 + scolE, (char*)sA + wid * 1024);
        }
        // B: 12KB = 8KB (all waves) + 4KB (waves 0-3)
        {
            const int n = wid * 8 + rowIn;
            int grow = a * NCHN + n;
            grow = grow > (OUT_CH - 1) ? (OUT_CH - 1) : grow;
            gload16(Wb + (size_t)grow * C + k0 + scolE, (char*)sB + wid * 1024);
        }
        if (wid < 4) {
            const int n = 64 + wid * 8 + rowIn;
            int grow = a * NCHN + n;
            grow = grow > (OUT_CH - 1) ? (OUT_CH - 1) : grow;
            gload16(Wb + (size_t)grow * C + k0 + scolE, (char*)sB + 8192 + wid * 1024);
        }
    };

    auto compute = [&](int bufsel) {
        const unsigned short* sA = sAbase + bufsel * 4096;
        const unsigned short* sB = sBbase + bufsel * 6144;
        #pragma unroll
        for (int kk = 0; kk < 2; ++kk) {
            const int cb = (kk << 6) + kqb;
            const int ra = wm * 16 + lr;
            const short8 af = *(const short8*)((const char*)sA + ra * 128 + (cb ^ swzR));
            short8 bfr[3];
            #pragma unroll
            for (int j = 0; j < 3; ++j) {
                const int rb = wn * 48 + j * 16 + lr;
                bfr[j] = *(const short8*)((const char*)sB + rb * 128 + (cb ^ swzR));
            }
            #pragma unroll
            for (int j = 0; j < 3; ++j)
                acc[j] = __builtin_amdgcn_mfma_f32_16x16x32_bf16(af, bfr[j], acc[j], 0, 0, 0);
        }
    };

    // prologue + 2-phase pipelined K loop (issue next-tile loads BEFORE compute)
    stage(0, 0);
    __syncthreads();
    int cur = 0;
    for (int kt = 0; kt < KT; ++kt) {
        if (kt + 1 < KT) stage(cur ^ 1, kt + 1);
        compute(cur);
        __syncthreads();          // drains this iteration's prefetch loads too
        cur ^= 1;
    }

    // ---- epilogue: decode into flat LDS image [64 px][86 ch], then stream out ----
    // C/D layout: col(N)=lane&15, row(M)=(lane>>4)*4+reg
    const int rq = (lane >> 4) * 4;
    const int lvloff = lvl1 ? 73728 : 0;

    #pragma unroll
    for (int j = 0; j < 3; ++j) {
        const int ch = wn * 48 + j * 16 + lr;
        if (ch < NCHN) {
            const float bv = biasA[ch];
            #pragma unroll
            for (int r = 0; r < 4; ++r) {
                const int px = wm * 16 + rq + r;            // 0..63
                const int p  = p0 + px;                     // pixel in level grid
                const float vv = acc[j][r] + bv;
                float res;
                if (ch == 0)      res = (sigm(vv) * sxy - sxy_off + (float)(p & ((1 << Gsh) - 1))) * sf;
                else if (ch == 1) res = (sigm(vv) * sxy - sxy_off + (float)(p >> Gsh)) * sf;
                else if (ch == 2) res = __expf(vv) * aw;
                else if (ch == 3) res = __expf(vv) * ah;
                else if (ch == 4) res = vv + aa;
                else              res = sigm(vv);
                sOutF[px * NCHN + ch] = res;
            }
        }
    }
    __syncthreads();

    // stream out: block span = 64*86 = 5504 dwords, contiguous & 16B-aligned.
    // NON-TEMPORAL stores (ext-vector f32x4 for the builtin): output is
    // write-once, never re-read -> bypass L2 allocation (the ~2 TB/s
    // dirty-eviction ceiling seen in R4-R6).
    const size_t spanDw = (size_t)b * BPB + ((size_t)(lvloff + a * GG + p0)) * NCHN;
    #pragma unroll
    for (int k = 0; k < 3; ++k) {
        const int f4 = tid + k * 512;       // float4 index, 1376 total
        if (f4 < 1376) {
            const f32x4 vv = *(const f32x4*)&sOutF[f4 * 4];
            __builtin_nontemporal_store(vv, (f32x4*)&out[spanDw + f4 * 4]);
        }
    }
}

extern "C" void kernel_launch(void* const* d_in, const int* in_sizes, int n_in,
                              void* d_out, int out_size, void* d_ws, size_t ws_size,
                              hipStream_t stream) {
    const float* x0 = (const float*)d_in[0];
    const float* x1 = (const float*)d_in[1];
    const float* W0 = (const float*)d_in[2];
    const float* b0 = (const float*)d_in[3];
    const float* W1 = (const float*)d_in[4];
    const float* b1 = (const float*)d_in[5];
    float* out = (float*)d_out;

    // workspace layout (bytes)
    constexpr size_t XB0_OFF = 0;            // 8*4096*256*2  = 16777216
    constexpr size_t XB1_OFF = 16777216;     // 8*1024*512*2  =  8388608
    constexpr size_t WB0_OFF = 25165824;     // 1548*256*2    =   792576
    constexpr size_t WB1_OFF = 25958400;     // 1548*512*2    =  1585152

    unsigned short* Xb0 = (unsigned short*)((char*)d_ws + XB0_OFF);
    unsigned short* Xb1 = (unsigned short*)((char*)d_ws + XB1_OFF);
    unsigned short* Wb0 = (unsigned short*)((char*)d_ws + WB0_OFF);
    unsigned short* Wb1 = (unsigned short*)((char*)d_ws + WB1_OFF);

    hipLaunchKernelGGL(conv_w_kernel, dim3((297216 + 255) / 256), dim3(256), 0, stream,
                       W0, Wb0, W1, Wb1);
    hipLaunchKernelGGL(transpose_x_kernel, dim3(64, 4, 8), dim3(256), 0, stream,
                       x0, Xb0, 256, 4096);
    hipLaunchKernelGGL(transpose_x_kernel, dim3(16, 8, 8), dim3(256), 0, stream,
                       x1, Xb1, 512, 1024);

    // 640 mtiles (512 lvl0 + 128 lvl1) x 18 anchors = 11520 blocks
    hipLaunchKernelGGL(detect_gemm, dim3(11520), dim3(512), 0, stream,
                       Xb0, Xb1, Wb0, Wb1, b0, b1, out);
}